// Round 2
// baseline (6802.679 us; speedup 1.0000x reference)
//
#include <hip/hip_runtime.h>
#include <cstdint>

#define TT 128
#define INW 64
#define HH 2048
#define OUTW 4096

// ws layout (floats):
//     0 : h0buf[2][2048]   (ping-pong, parity t&1 = input of step t)
//  4096 : h1buf[2][2048]
//  8192 : c0[2048]
// 10240 : c1[2048]
// 12288 : logits[4096]
// 16384 : partials float4[256]  (m, s, gmax, idx_bits)

__device__ __forceinline__ uint32_t rotl32(uint32_t x, int r) {
  return (x << r) | (x >> (32 - r));
}

#define TF_ROUND(r) do { x0 += x1; x1 = rotl32(x1, r); x1 ^= x0; } while (0)

// Exact JAX threefry2x32 (5 groups of 4 rounds, key schedule every 4)
__device__ __forceinline__ void threefry2x32(uint32_t k0, uint32_t k1,
                                             uint32_t c0, uint32_t c1,
                                             uint32_t& o0, uint32_t& o1) {
  uint32_t ks2 = k0 ^ k1 ^ 0x1BD11BDAu;
  uint32_t x0 = c0 + k0;
  uint32_t x1 = c1 + k1;
  TF_ROUND(13); TF_ROUND(15); TF_ROUND(26); TF_ROUND(6);
  x0 += k1;  x1 += ks2 + 1u;
  TF_ROUND(17); TF_ROUND(29); TF_ROUND(16); TF_ROUND(24);
  x0 += ks2; x1 += k0 + 2u;
  TF_ROUND(13); TF_ROUND(15); TF_ROUND(26); TF_ROUND(6);
  x0 += k0;  x1 += k1 + 3u;
  TF_ROUND(17); TF_ROUND(29); TF_ROUND(16); TF_ROUND(24);
  x0 += k1;  x1 += ks2 + 4u;
  TF_ROUND(13); TF_ROUND(15); TF_ROUND(26); TF_ROUND(6);
  x0 += ks2; x1 += k0 + 5u;
  o0 = x0; o1 = x1;
}

// jax_threefry_partitionable=True (default in modern JAX):
// split(key, 128): keys[t] = threefry2x32((0,42), c0=hi(t)=0, c1=lo(t)=t) -> (y0, y1)
__device__ __forceinline__ void step_key(int t, uint32_t& k0, uint32_t& k1) {
  threefry2x32(0u, 42u, 0u, (uint32_t)t, k0, k1);
}

// random_bits(key, 32, (1,4096)) partitionable: bits[j] = y0 ^ y1 of
// threefry2x32(key, c0=hi(j)=0, c1=lo(j)=j)
__device__ __forceinline__ float gumbel_for(uint32_t k0, uint32_t k1, int j) {
  uint32_t o0, o1;
  threefry2x32(k0, k1, 0u, (uint32_t)j, o0, o1);
  uint32_t bits = o0 ^ o1;
  uint32_t fb = (bits >> 9) | 0x3f800000u;
  float f = __uint_as_float(fb) - 1.0f;              // [0, 1)
  float u = fmaxf(f, 1.1754943508222875e-38f);       // jax uniform(minval=tiny)
  return -logf(-logf(u));
}

__device__ __forceinline__ float wave_sum(float v) {
  v += __shfl_xor(v, 1, 64);
  v += __shfl_xor(v, 2, 64);
  v += __shfl_xor(v, 4, 64);
  v += __shfl_xor(v, 8, 64);
  v += __shfl_xor(v, 16, 64);
  v += __shfl_xor(v, 32, 64);
  return v;
}

__device__ __forceinline__ float sigf(float x) { return 1.0f / (1.0f + expf(-x)); }

// combine (max, sumexp, gumbel-argmax) partials; a covers LOWER indices (tie -> a)
__device__ __forceinline__ float4 combine2(float4 a, float4 b) {
  float M = fmaxf(a.x, b.x);
  float S = a.y * expf(a.x - M) + b.y * expf(b.x - M);
  float g, w;
  if (b.z > a.z) { g = b.z; w = b.w; } else { g = a.z; w = a.w; }
  return make_float4(M, S, g, w);
}

__global__ __launch_bounds__(256) void k_init(const float* __restrict__ h0i,
                                              const float* __restrict__ c0i,
                                              float* __restrict__ ws) {
  int i = blockIdx.x * 256 + threadIdx.x;  // 2048 total
  ws[i] = h0i[i];                  // h0buf parity 0
  ws[4096 + i] = h0i[2048 + i];    // h1buf parity 0
  ws[8192 + i] = c0i[i];           // c0
  ws[10240 + i] = c0i[2048 + i];   // c1
}

// K1: finalize step t-1 (sample + probs from partials), then layer0 of step t.
// grid 512 x 256; block b computes h0 elements j = b*4 + wave.
__global__ __launch_bounds__(256) void k_layer0(
    const float* __restrict__ input,
    const float* __restrict__ Wih0, const float* __restrict__ Whh0,
    const float* __restrict__ bih0, const float* __restrict__ bhh0,
    float* __restrict__ ws, float* __restrict__ out, int t) {
  __shared__ float h0s[HH];
  __shared__ float xa[72];
  __shared__ float4 red[256];

  float* h0buf = ws;
  float* c0 = ws + 8192;
  float* logits = ws + 12288;
  float4* partials = (float4*)(ws + 16384);

  const float* h0_in = h0buf + (t & 1) * HH;
  float* h0_out = h0buf + ((t + 1) & 1) * HH;

  const int tid = threadIdx.x;
  const int b = blockIdx.x;

  float prev;
  if (t > 0) {
    red[tid] = partials[tid];
    __syncthreads();
    for (int off = 128; off > 0; off >>= 1) {
      if (tid < off) red[tid] = combine2(red[tid], red[tid + off]);
      __syncthreads();
    }
    float4 r = red[0];
    int samp = __float_as_int(r.w);
    prev = (float)samp;
    // probs for step t-1: 8 per block
    if (tid < 8) {
      int j = b * 8 + tid;
      out[TT + (size_t)(t - 1) * OUTW + j] = expf(logits[j] - r.x) / r.y;
    }
    if (b == 0 && tid == 0) out[t - 1] = (float)samp;
  } else {
    prev = 1.0f;
  }

  // stage xa and h0
  if (tid == 0) xa[0] = prev;
  if (tid >= 1 && tid <= 64) xa[tid] = input[t * INW + tid - 1];
  for (int k = 0; k < HH / 256; ++k) h0s[tid + 256 * k] = h0_in[tid + 256 * k];
  __syncthreads();

  const int wave = tid >> 6, lane = tid & 63;
  const int j = b * 4 + wave;

  float acc0 = 0.f, acc1 = 0.f, acc2 = 0.f, acc3 = 0.f;
  // input part (65 wide)
  {
    float xl = xa[lane];
    acc0 += Wih0[(size_t)(0 * HH + j) * 65 + lane] * xl;
    acc1 += Wih0[(size_t)(1 * HH + j) * 65 + lane] * xl;
    acc2 += Wih0[(size_t)(2 * HH + j) * 65 + lane] * xl;
    acc3 += Wih0[(size_t)(3 * HH + j) * 65 + lane] * xl;
    if (lane == 0) {
      float xe = xa[64];
      acc0 += Wih0[(size_t)(0 * HH + j) * 65 + 64] * xe;
      acc1 += Wih0[(size_t)(1 * HH + j) * 65 + 64] * xe;
      acc2 += Wih0[(size_t)(2 * HH + j) * 65 + 64] * xe;
      acc3 += Wih0[(size_t)(3 * HH + j) * 65 + 64] * xe;
    }
  }
  // recurrent part
  const float4* h4 = (const float4*)h0s;
  const float4* w0 = (const float4*)(Whh0 + (size_t)(0 * HH + j) * HH);
  const float4* w1 = (const float4*)(Whh0 + (size_t)(1 * HH + j) * HH);
  const float4* w2 = (const float4*)(Whh0 + (size_t)(2 * HH + j) * HH);
  const float4* w3 = (const float4*)(Whh0 + (size_t)(3 * HH + j) * HH);
  for (int s = 0; s < HH / 256; ++s) {
    int e = s * 64 + lane;
    float4 hv = h4[e];
    float4 a = w0[e];
    float4 bb = w1[e];
    float4 cc = w2[e];
    float4 dd = w3[e];
    acc0 += a.x * hv.x + a.y * hv.y + a.z * hv.z + a.w * hv.w;
    acc1 += bb.x * hv.x + bb.y * hv.y + bb.z * hv.z + bb.w * hv.w;
    acc2 += cc.x * hv.x + cc.y * hv.y + cc.z * hv.z + cc.w * hv.w;
    acc3 += dd.x * hv.x + dd.y * hv.y + dd.z * hv.z + dd.w * hv.w;
  }
  acc0 = wave_sum(acc0);
  acc1 = wave_sum(acc1);
  acc2 = wave_sum(acc2);
  acc3 = wave_sum(acc3);
  if (lane == 0) {
    float gi_ = acc0 + bih0[0 * HH + j] + bhh0[0 * HH + j];
    float gf_ = acc1 + bih0[1 * HH + j] + bhh0[1 * HH + j];
    float gg_ = acc2 + bih0[2 * HH + j] + bhh0[2 * HH + j];
    float go_ = acc3 + bih0[3 * HH + j] + bhh0[3 * HH + j];
    float c = c0[j];
    float cn = sigf(gf_) * c + sigf(gi_) * tanhf(gg_);
    c0[j] = cn;
    h0_out[j] = sigf(go_) * tanhf(cn);
  }
}

// K2: layer1. grid 512 x 256; j = b*4 + wave.
__global__ __launch_bounds__(256) void k_layer1(
    const float* __restrict__ Wih1, const float* __restrict__ Whh1,
    const float* __restrict__ bih1, const float* __restrict__ bhh1,
    float* __restrict__ ws, int t) {
  __shared__ float xs[HH];  // h0n
  __shared__ float hs[HH];  // h1 old
  float* h0buf = ws;
  float* h1buf = ws + 4096;
  float* c1 = ws + 10240;
  const float* x_in = h0buf + ((t + 1) & 1) * HH;
  const float* h_in = h1buf + (t & 1) * HH;
  float* h_out = h1buf + ((t + 1) & 1) * HH;

  const int tid = threadIdx.x;
  const int b = blockIdx.x;
  for (int k = 0; k < HH / 256; ++k) {
    xs[tid + 256 * k] = x_in[tid + 256 * k];
    hs[tid + 256 * k] = h_in[tid + 256 * k];
  }
  __syncthreads();

  const int wave = tid >> 6, lane = tid & 63;
  const int j = b * 4 + wave;

  float acc0 = 0.f, acc1 = 0.f, acc2 = 0.f, acc3 = 0.f;
  const float4* x4 = (const float4*)xs;
  const float4* h4 = (const float4*)hs;
  const float4* wi0 = (const float4*)(Wih1 + (size_t)(0 * HH + j) * HH);
  const float4* wi1 = (const float4*)(Wih1 + (size_t)(1 * HH + j) * HH);
  const float4* wi2 = (const float4*)(Wih1 + (size_t)(2 * HH + j) * HH);
  const float4* wi3 = (const float4*)(Wih1 + (size_t)(3 * HH + j) * HH);
  const float4* wh0 = (const float4*)(Whh1 + (size_t)(0 * HH + j) * HH);
  const float4* wh1 = (const float4*)(Whh1 + (size_t)(1 * HH + j) * HH);
  const float4* wh2 = (const float4*)(Whh1 + (size_t)(2 * HH + j) * HH);
  const float4* wh3 = (const float4*)(Whh1 + (size_t)(3 * HH + j) * HH);
  for (int s = 0; s < HH / 256; ++s) {
    int e = s * 64 + lane;
    float4 xv = x4[e];
    float4 hv = h4[e];
    float4 a, bb;
    a = wi0[e]; acc0 += a.x * xv.x + a.y * xv.y + a.z * xv.z + a.w * xv.w;
    a = wi1[e]; acc1 += a.x * xv.x + a.y * xv.y + a.z * xv.z + a.w * xv.w;
    a = wi2[e]; acc2 += a.x * xv.x + a.y * xv.y + a.z * xv.z + a.w * xv.w;
    a = wi3[e]; acc3 += a.x * xv.x + a.y * xv.y + a.z * xv.z + a.w * xv.w;
    bb = wh0[e]; acc0 += bb.x * hv.x + bb.y * hv.y + bb.z * hv.z + bb.w * hv.w;
    bb = wh1[e]; acc1 += bb.x * hv.x + bb.y * hv.y + bb.z * hv.z + bb.w * hv.w;
    bb = wh2[e]; acc2 += bb.x * hv.x + bb.y * hv.y + bb.z * hv.z + bb.w * hv.w;
    bb = wh3[e]; acc3 += bb.x * hv.x + bb.y * hv.y + bb.z * hv.z + bb.w * hv.w;
  }
  acc0 = wave_sum(acc0);
  acc1 = wave_sum(acc1);
  acc2 = wave_sum(acc2);
  acc3 = wave_sum(acc3);
  if (lane == 0) {
    float gi_ = acc0 + bih1[0 * HH + j] + bhh1[0 * HH + j];
    float gf_ = acc1 + bih1[1 * HH + j] + bhh1[1 * HH + j];
    float gg_ = acc2 + bih1[2 * HH + j] + bhh1[2 * HH + j];
    float go_ = acc3 + bih1[3 * HH + j] + bhh1[3 * HH + j];
    float c = c1[j];
    float cn = sigf(gf_) * c + sigf(gi_) * tanhf(gg_);
    c1[j] = cn;
    h_out[j] = sigf(go_) * tanhf(cn);
  }
}

// K3: logits + gumbel + per-block partials. grid 256 x 256; 16 logits per block.
__global__ __launch_bounds__(256) void k_logits(
    const float* __restrict__ Wl, const float* __restrict__ bl,
    float* __restrict__ ws, int t) {
  __shared__ float hs[HH];
  __shared__ float lv[16];
  __shared__ float gv[16];
  __shared__ uint32_t kk[2];

  float* h1buf = ws + 4096;
  const float* h1n = h1buf + ((t + 1) & 1) * HH;
  float* logits = ws + 12288;
  float4* partials = (float4*)(ws + 16384);

  const int tid = threadIdx.x;
  const int b = blockIdx.x;
  if (tid == 0) {
    uint32_t k0, k1;
    step_key(t, k0, k1);
    kk[0] = k0; kk[1] = k1;
  }
  for (int k = 0; k < HH / 256; ++k) hs[tid + 256 * k] = h1n[tid + 256 * k];
  __syncthreads();

  const int wave = tid >> 6, lane = tid & 63;
  const float4* h4 = (const float4*)hs;
  for (int q = 0; q < 4; ++q) {
    int jl = wave * 4 + q;
    int j = b * 16 + jl;
    const float4* wr = (const float4*)(Wl + (size_t)j * HH);
    float acc = 0.f;
    for (int s = 0; s < HH / 256; ++s) {
      int e = s * 64 + lane;
      float4 w = wr[e];
      float4 h = h4[e];
      acc += w.x * h.x + w.y * h.y + w.z * h.z + w.w * h.w;
    }
    acc = wave_sum(acc);
    if (lane == 0) {
      float l = acc + bl[j];
      logits[j] = l;
      lv[jl] = l;
      gv[jl] = l + gumbel_for(kk[0], kk[1], j);
    }
  }
  __syncthreads();
  if (tid == 0) {
    float m = -INFINITY, s = 0.f, gm = -INFINITY;
    int gi = 0;
    for (int k = 0; k < 16; ++k) {
      float l = lv[k];
      float m2 = fmaxf(m, l);
      s = s * expf(m - m2) + expf(l - m2);
      m = m2;
      float g = gv[k];
      if (g > gm) { gm = g; gi = b * 16 + k; }
    }
    partials[b] = make_float4(m, s, gm, __int_as_float(gi));
  }
}

// K_final: finalize step 127. grid 256 x 256; 16 probs per block.
__global__ __launch_bounds__(256) void k_final(float* __restrict__ ws,
                                               float* __restrict__ out) {
  __shared__ float4 red[256];
  float* logits = ws + 12288;
  float4* partials = (float4*)(ws + 16384);
  const int tid = threadIdx.x;
  const int b = blockIdx.x;
  red[tid] = partials[tid];
  __syncthreads();
  for (int off = 128; off > 0; off >>= 1) {
    if (tid < off) red[tid] = combine2(red[tid], red[tid + off]);
    __syncthreads();
  }
  float4 r = red[0];
  if (tid < 16) {
    int j = b * 16 + tid;
    out[TT + (size_t)(TT - 1) * OUTW + j] = expf(logits[j] - r.x) / r.y;
  }
  if (b == 0 && tid == 0) out[TT - 1] = (float)__float_as_int(r.w);
}

extern "C" void kernel_launch(void* const* d_in, const int* in_sizes, int n_in,
                              void* d_out, int out_size, void* d_ws, size_t ws_size,
                              hipStream_t stream) {
  (void)in_sizes; (void)n_in; (void)out_size; (void)ws_size;
  const float* input = (const float*)d_in[0];
  const float* h0i  = (const float*)d_in[1];
  const float* c0i  = (const float*)d_in[2];
  const float* Wih0 = (const float*)d_in[3];
  const float* Whh0 = (const float*)d_in[4];
  const float* bih0 = (const float*)d_in[5];
  const float* bhh0 = (const float*)d_in[6];
  const float* Wih1 = (const float*)d_in[7];
  const float* Whh1 = (const float*)d_in[8];
  const float* bih1 = (const float*)d_in[9];
  const float* bhh1 = (const float*)d_in[10];
  const float* Wl   = (const float*)d_in[11];
  const float* bl   = (const float*)d_in[12];
  float* out = (float*)d_out;
  float* ws = (float*)d_ws;

  k_init<<<8, 256, 0, stream>>>(h0i, c0i, ws);
  for (int t = 0; t < TT; ++t) {
    k_layer0<<<512, 256, 0, stream>>>(input, Wih0, Whh0, bih0, bhh0, ws, out, t);
    k_layer1<<<512, 256, 0, stream>>>(Wih1, Whh1, bih1, bhh1, ws, t);
    k_logits<<<256, 256, 0, stream>>>(Wl, bl, ws, t);
  }
  k_final<<<256, 256, 0, stream>>>(ws, out);
}

// Round 3
// 4786.378 us; speedup vs baseline: 1.4213x; 1.4213x over previous
//
#include <hip/hip_runtime.h>
#include <cstdint>

#define TT 128
#define INW 64
#define HH 2048
#define OUTW 4096

typedef _Float16 half8 __attribute__((ext_vector_type(8)));

// ws layout:
//   floats (state):
//       0 : h0buf[2][2048]   (ping-pong, parity t&1 = input of step t)
//    4096 : h1buf[2][2048]
//    8192 : c0[2048]
//   10240 : c1[2048]
//   12288 : logits[4096]
//   16384 : partials float4[256]  (m, s, gmax, idx_bits)  (ends 17408)
//   bytes (fp16 weights, when ws_size permits), base 131072 B:
//   Whh0h 33554432 B | Wih1h 33554432 B | Whh1h 33554432 B | Wlh 16777216 B
#define W16_BASE 131072ull
#define SZ_HH (16777216ull * 2)   // 4H*H halves in bytes
#define WS_F16_NEED (W16_BASE + 3 * SZ_HH + 16777216ull)

__device__ __forceinline__ uint32_t rotl32(uint32_t x, int r) {
  return (x << r) | (x >> (32 - r));
}

#define TF_ROUND(r) do { x0 += x1; x1 = rotl32(x1, r); x1 ^= x0; } while (0)

__device__ __forceinline__ void threefry2x32(uint32_t k0, uint32_t k1,
                                             uint32_t c0, uint32_t c1,
                                             uint32_t& o0, uint32_t& o1) {
  uint32_t ks2 = k0 ^ k1 ^ 0x1BD11BDAu;
  uint32_t x0 = c0 + k0;
  uint32_t x1 = c1 + k1;
  TF_ROUND(13); TF_ROUND(15); TF_ROUND(26); TF_ROUND(6);
  x0 += k1;  x1 += ks2 + 1u;
  TF_ROUND(17); TF_ROUND(29); TF_ROUND(16); TF_ROUND(24);
  x0 += ks2; x1 += k0 + 2u;
  TF_ROUND(13); TF_ROUND(15); TF_ROUND(26); TF_ROUND(6);
  x0 += k0;  x1 += k1 + 3u;
  TF_ROUND(17); TF_ROUND(29); TF_ROUND(16); TF_ROUND(24);
  x0 += k1;  x1 += ks2 + 4u;
  TF_ROUND(13); TF_ROUND(15); TF_ROUND(26); TF_ROUND(6);
  x0 += ks2; x1 += k0 + 5u;
  o0 = x0; o1 = x1;
}

// jax_threefry_partitionable=True semantics (verified passing in round 2)
__device__ __forceinline__ void step_key(int t, uint32_t& k0, uint32_t& k1) {
  threefry2x32(0u, 42u, 0u, (uint32_t)t, k0, k1);
}

__device__ __forceinline__ float gumbel_for(uint32_t k0, uint32_t k1, int j) {
  uint32_t o0, o1;
  threefry2x32(k0, k1, 0u, (uint32_t)j, o0, o1);
  uint32_t bits = o0 ^ o1;
  uint32_t fb = (bits >> 9) | 0x3f800000u;
  float f = __uint_as_float(fb) - 1.0f;
  float u = fmaxf(f, 1.1754943508222875e-38f);
  return -logf(-logf(u));
}

__device__ __forceinline__ float wave_sum(float v) {
  v += __shfl_xor(v, 1, 64);
  v += __shfl_xor(v, 2, 64);
  v += __shfl_xor(v, 4, 64);
  v += __shfl_xor(v, 8, 64);
  v += __shfl_xor(v, 16, 64);
  v += __shfl_xor(v, 32, 64);
  return v;
}

__device__ __forceinline__ float sigf(float x) { return 1.0f / (1.0f + expf(-x)); }

__device__ __forceinline__ float4 combine2(float4 a, float4 b) {
  float M = fmaxf(a.x, b.x);
  float S = a.y * expf(a.x - M) + b.y * expf(b.x - M);
  float g, w;
  if (b.z > a.z) { g = b.z; w = b.w; } else { g = a.z; w = a.w; }
  return make_float4(M, S, g, w);
}

// dot of 8 fp16 weights vs 8 fp32 activations (two float4s)
__device__ __forceinline__ float dot8(half8 a, float4 v0, float4 v1) {
  return (float)a[0] * v0.x + (float)a[1] * v0.y + (float)a[2] * v0.z +
         (float)a[3] * v0.w + (float)a[4] * v1.x + (float)a[5] * v1.y +
         (float)a[6] * v1.z + (float)a[7] * v1.w;
}

__global__ __launch_bounds__(256) void k_convert(const float* __restrict__ src,
                                                 _Float16* __restrict__ dst, int n8) {
  int i = blockIdx.x * 256 + threadIdx.x;
  if (i < n8) {
    const float4* s = (const float4*)src;
    float4 a = s[2 * i], b = s[2 * i + 1];
    half8 h;
    h[0] = (_Float16)a.x; h[1] = (_Float16)a.y; h[2] = (_Float16)a.z; h[3] = (_Float16)a.w;
    h[4] = (_Float16)b.x; h[5] = (_Float16)b.y; h[6] = (_Float16)b.z; h[7] = (_Float16)b.w;
    ((half8*)dst)[i] = h;
  }
}

__global__ __launch_bounds__(256) void k_init(const float* __restrict__ h0i,
                                              const float* __restrict__ c0i,
                                              float* __restrict__ ws) {
  int i = blockIdx.x * 256 + threadIdx.x;  // 2048 total
  ws[i] = h0i[i];
  ws[4096 + i] = h0i[2048 + i];
  ws[8192 + i] = c0i[i];
  ws[10240 + i] = c0i[2048 + i];
}

// ---------------- fp16-weight path ----------------

// K1: finalize step t-1 (sample + probs), then layer0 of step t.
// grid 512 x 256; block b computes h0 elements j = b*4 + wave.
__global__ __launch_bounds__(256) void k_layer0_f16(
    const float* __restrict__ input,
    const float* __restrict__ Wih0, const _Float16* __restrict__ Whh0h,
    const float* __restrict__ bih0, const float* __restrict__ bhh0,
    float* __restrict__ ws, float* __restrict__ out, int t) {
  __shared__ float h0s[HH];
  __shared__ float xa[72];
  __shared__ float4 red[256];

  float* h0buf = ws;
  float* c0 = ws + 8192;
  float* logits = ws + 12288;
  float4* partials = (float4*)(ws + 16384);

  const float* h0_in = h0buf + (t & 1) * HH;
  float* h0_out = h0buf + ((t + 1) & 1) * HH;

  const int tid = threadIdx.x;
  const int b = blockIdx.x;

  float prev;
  if (t > 0) {
    red[tid] = partials[tid];
    __syncthreads();
    for (int off = 128; off > 0; off >>= 1) {
      if (tid < off) red[tid] = combine2(red[tid], red[tid + off]);
      __syncthreads();
    }
    float4 r = red[0];
    int samp = __float_as_int(r.w);
    prev = (float)samp;
    if (tid < 8) {
      int j = b * 8 + tid;
      out[TT + (size_t)(t - 1) * OUTW + j] = expf(logits[j] - r.x) / r.y;
    }
    if (b == 0 && tid == 0) out[t - 1] = (float)samp;
  } else {
    prev = 1.0f;
  }

  if (tid == 0) xa[0] = prev;
  if (tid >= 1 && tid <= 64) xa[tid] = input[t * INW + tid - 1];
  for (int k = 0; k < HH / 256; ++k) h0s[tid + 256 * k] = h0_in[tid + 256 * k];
  __syncthreads();

  const int wave = tid >> 6, lane = tid & 63;
  const int j = b * 4 + wave;

  float acc0 = 0.f, acc1 = 0.f, acc2 = 0.f, acc3 = 0.f;
  // input part in fp32 (column 0 carries the sampled index — keep exact)
  {
    float xl = xa[lane];
    acc0 += Wih0[(size_t)(0 * HH + j) * 65 + lane] * xl;
    acc1 += Wih0[(size_t)(1 * HH + j) * 65 + lane] * xl;
    acc2 += Wih0[(size_t)(2 * HH + j) * 65 + lane] * xl;
    acc3 += Wih0[(size_t)(3 * HH + j) * 65 + lane] * xl;
    if (lane == 0) {
      float xe = xa[64];
      acc0 += Wih0[(size_t)(0 * HH + j) * 65 + 64] * xe;
      acc1 += Wih0[(size_t)(1 * HH + j) * 65 + 64] * xe;
      acc2 += Wih0[(size_t)(2 * HH + j) * 65 + 64] * xe;
      acc3 += Wih0[(size_t)(3 * HH + j) * 65 + 64] * xe;
    }
  }
  const float4* h4 = (const float4*)h0s;
  const half8* w0 = (const half8*)(Whh0h + (size_t)(0 * HH + j) * HH);
  const half8* w1 = (const half8*)(Whh0h + (size_t)(1 * HH + j) * HH);
  const half8* w2 = (const half8*)(Whh0h + (size_t)(2 * HH + j) * HH);
  const half8* w3 = (const half8*)(Whh0h + (size_t)(3 * HH + j) * HH);
  for (int s = 0; s < 4; ++s) {
    int idx = s * 64 + lane;          // 0..255 half8 chunks
    float4 v0 = h4[2 * idx], v1 = h4[2 * idx + 1];
    acc0 += dot8(w0[idx], v0, v1);
    acc1 += dot8(w1[idx], v0, v1);
    acc2 += dot8(w2[idx], v0, v1);
    acc3 += dot8(w3[idx], v0, v1);
  }
  acc0 = wave_sum(acc0);
  acc1 = wave_sum(acc1);
  acc2 = wave_sum(acc2);
  acc3 = wave_sum(acc3);
  if (lane == 0) {
    float gi_ = acc0 + bih0[0 * HH + j] + bhh0[0 * HH + j];
    float gf_ = acc1 + bih0[1 * HH + j] + bhh0[1 * HH + j];
    float gg_ = acc2 + bih0[2 * HH + j] + bhh0[2 * HH + j];
    float go_ = acc3 + bih0[3 * HH + j] + bhh0[3 * HH + j];
    float c = c0[j];
    float cn = sigf(gf_) * c + sigf(gi_) * tanhf(gg_);
    c0[j] = cn;
    h0_out[j] = sigf(go_) * tanhf(cn);
  }
}

// K2: layer1, fp16 weights. grid 512 x 256; j = b*4 + wave.
__global__ __launch_bounds__(256) void k_layer1_f16(
    const _Float16* __restrict__ Wih1h, const _Float16* __restrict__ Whh1h,
    const float* __restrict__ bih1, const float* __restrict__ bhh1,
    float* __restrict__ ws, int t) {
  __shared__ float xs[HH];
  __shared__ float hs[HH];
  float* h0buf = ws;
  float* h1buf = ws + 4096;
  float* c1 = ws + 10240;
  const float* x_in = h0buf + ((t + 1) & 1) * HH;
  const float* h_in = h1buf + (t & 1) * HH;
  float* h_out = h1buf + ((t + 1) & 1) * HH;

  const int tid = threadIdx.x;
  const int b = blockIdx.x;
  for (int k = 0; k < HH / 256; ++k) {
    xs[tid + 256 * k] = x_in[tid + 256 * k];
    hs[tid + 256 * k] = h_in[tid + 256 * k];
  }
  __syncthreads();

  const int wave = tid >> 6, lane = tid & 63;
  const int j = b * 4 + wave;

  float acc0 = 0.f, acc1 = 0.f, acc2 = 0.f, acc3 = 0.f;
  const float4* x4 = (const float4*)xs;
  const float4* h4 = (const float4*)hs;
  const half8* wi0 = (const half8*)(Wih1h + (size_t)(0 * HH + j) * HH);
  const half8* wi1 = (const half8*)(Wih1h + (size_t)(1 * HH + j) * HH);
  const half8* wi2 = (const half8*)(Wih1h + (size_t)(2 * HH + j) * HH);
  const half8* wi3 = (const half8*)(Wih1h + (size_t)(3 * HH + j) * HH);
  const half8* wh0 = (const half8*)(Whh1h + (size_t)(0 * HH + j) * HH);
  const half8* wh1 = (const half8*)(Whh1h + (size_t)(1 * HH + j) * HH);
  const half8* wh2 = (const half8*)(Whh1h + (size_t)(2 * HH + j) * HH);
  const half8* wh3 = (const half8*)(Whh1h + (size_t)(3 * HH + j) * HH);
  for (int s = 0; s < 4; ++s) {
    int idx = s * 64 + lane;
    float4 xv0 = x4[2 * idx], xv1 = x4[2 * idx + 1];
    float4 hv0 = h4[2 * idx], hv1 = h4[2 * idx + 1];
    acc0 += dot8(wi0[idx], xv0, xv1);
    acc1 += dot8(wi1[idx], xv0, xv1);
    acc2 += dot8(wi2[idx], xv0, xv1);
    acc3 += dot8(wi3[idx], xv0, xv1);
    acc0 += dot8(wh0[idx], hv0, hv1);
    acc1 += dot8(wh1[idx], hv0, hv1);
    acc2 += dot8(wh2[idx], hv0, hv1);
    acc3 += dot8(wh3[idx], hv0, hv1);
  }
  acc0 = wave_sum(acc0);
  acc1 = wave_sum(acc1);
  acc2 = wave_sum(acc2);
  acc3 = wave_sum(acc3);
  if (lane == 0) {
    float gi_ = acc0 + bih1[0 * HH + j] + bhh1[0 * HH + j];
    float gf_ = acc1 + bih1[1 * HH + j] + bhh1[1 * HH + j];
    float gg_ = acc2 + bih1[2 * HH + j] + bhh1[2 * HH + j];
    float go_ = acc3 + bih1[3 * HH + j] + bhh1[3 * HH + j];
    float c = c1[j];
    float cn = sigf(gf_) * c + sigf(gi_) * tanhf(gg_);
    c1[j] = cn;
    h_out[j] = sigf(go_) * tanhf(cn);
  }
}

// K3: logits + gumbel + per-block partials, fp16 Wl. grid 256 x 256.
__global__ __launch_bounds__(256) void k_logits_f16(
    const _Float16* __restrict__ Wlh, const float* __restrict__ bl,
    float* __restrict__ ws, int t) {
  __shared__ float hs[HH];
  __shared__ float lv[16];
  __shared__ float gv[16];
  __shared__ uint32_t kk[2];

  float* h1buf = ws + 4096;
  const float* h1n = h1buf + ((t + 1) & 1) * HH;
  float* logits = ws + 12288;
  float4* partials = (float4*)(ws + 16384);

  const int tid = threadIdx.x;
  const int b = blockIdx.x;
  if (tid == 0) {
    uint32_t k0, k1;
    step_key(t, k0, k1);
    kk[0] = k0; kk[1] = k1;
  }
  for (int k = 0; k < HH / 256; ++k) hs[tid + 256 * k] = h1n[tid + 256 * k];
  __syncthreads();

  const int wave = tid >> 6, lane = tid & 63;
  const float4* h4 = (const float4*)hs;
  for (int q = 0; q < 4; ++q) {
    int jl = wave * 4 + q;
    int j = b * 16 + jl;
    const half8* wr = (const half8*)(Wlh + (size_t)j * HH);
    float acc = 0.f;
    for (int s = 0; s < 4; ++s) {
      int idx = s * 64 + lane;
      float4 v0 = h4[2 * idx], v1 = h4[2 * idx + 1];
      acc += dot8(wr[idx], v0, v1);
    }
    acc = wave_sum(acc);
    if (lane == 0) {
      float l = acc + bl[j];
      logits[j] = l;
      lv[jl] = l;
      gv[jl] = l + gumbel_for(kk[0], kk[1], j);
    }
  }
  __syncthreads();
  if (tid == 0) {
    float m = -INFINITY, s = 0.f, gm = -INFINITY;
    int gi = 0;
    for (int k = 0; k < 16; ++k) {
      float l = lv[k];
      float m2 = fmaxf(m, l);
      s = s * expf(m - m2) + expf(l - m2);
      m = m2;
      float g = gv[k];
      if (g > gm) { gm = g; gi = b * 16 + k; }
    }
    partials[b] = make_float4(m, s, gm, __int_as_float(gi));
  }
}

// ---------------- fp32 fallback path (round-2 proven kernels) ----------------

__global__ __launch_bounds__(256) void k_layer0(
    const float* __restrict__ input,
    const float* __restrict__ Wih0, const float* __restrict__ Whh0,
    const float* __restrict__ bih0, const float* __restrict__ bhh0,
    float* __restrict__ ws, float* __restrict__ out, int t) {
  __shared__ float h0s[HH];
  __shared__ float xa[72];
  __shared__ float4 red[256];

  float* h0buf = ws;
  float* c0 = ws + 8192;
  float* logits = ws + 12288;
  float4* partials = (float4*)(ws + 16384);

  const float* h0_in = h0buf + (t & 1) * HH;
  float* h0_out = h0buf + ((t + 1) & 1) * HH;

  const int tid = threadIdx.x;
  const int b = blockIdx.x;

  float prev;
  if (t > 0) {
    red[tid] = partials[tid];
    __syncthreads();
    for (int off = 128; off > 0; off >>= 1) {
      if (tid < off) red[tid] = combine2(red[tid], red[tid + off]);
      __syncthreads();
    }
    float4 r = red[0];
    int samp = __float_as_int(r.w);
    prev = (float)samp;
    if (tid < 8) {
      int j = b * 8 + tid;
      out[TT + (size_t)(t - 1) * OUTW + j] = expf(logits[j] - r.x) / r.y;
    }
    if (b == 0 && tid == 0) out[t - 1] = (float)samp;
  } else {
    prev = 1.0f;
  }

  if (tid == 0) xa[0] = prev;
  if (tid >= 1 && tid <= 64) xa[tid] = input[t * INW + tid - 1];
  for (int k = 0; k < HH / 256; ++k) h0s[tid + 256 * k] = h0_in[tid + 256 * k];
  __syncthreads();

  const int wave = tid >> 6, lane = tid & 63;
  const int j = b * 4 + wave;

  float acc0 = 0.f, acc1 = 0.f, acc2 = 0.f, acc3 = 0.f;
  {
    float xl = xa[lane];
    acc0 += Wih0[(size_t)(0 * HH + j) * 65 + lane] * xl;
    acc1 += Wih0[(size_t)(1 * HH + j) * 65 + lane] * xl;
    acc2 += Wih0[(size_t)(2 * HH + j) * 65 + lane] * xl;
    acc3 += Wih0[(size_t)(3 * HH + j) * 65 + lane] * xl;
    if (lane == 0) {
      float xe = xa[64];
      acc0 += Wih0[(size_t)(0 * HH + j) * 65 + 64] * xe;
      acc1 += Wih0[(size_t)(1 * HH + j) * 65 + 64] * xe;
      acc2 += Wih0[(size_t)(2 * HH + j) * 65 + 64] * xe;
      acc3 += Wih0[(size_t)(3 * HH + j) * 65 + 64] * xe;
    }
  }
  const float4* h4 = (const float4*)h0s;
  const float4* w0 = (const float4*)(Whh0 + (size_t)(0 * HH + j) * HH);
  const float4* w1 = (const float4*)(Whh0 + (size_t)(1 * HH + j) * HH);
  const float4* w2 = (const float4*)(Whh0 + (size_t)(2 * HH + j) * HH);
  const float4* w3 = (const float4*)(Whh0 + (size_t)(3 * HH + j) * HH);
  for (int s = 0; s < HH / 256; ++s) {
    int e = s * 64 + lane;
    float4 hv = h4[e];
    float4 a = w0[e];
    float4 bb = w1[e];
    float4 cc = w2[e];
    float4 dd = w3[e];
    acc0 += a.x * hv.x + a.y * hv.y + a.z * hv.z + a.w * hv.w;
    acc1 += bb.x * hv.x + bb.y * hv.y + bb.z * hv.z + bb.w * hv.w;
    acc2 += cc.x * hv.x + cc.y * hv.y + cc.z * hv.z + cc.w * hv.w;
    acc3 += dd.x * hv.x + dd.y * hv.y + dd.z * hv.z + dd.w * hv.w;
  }
  acc0 = wave_sum(acc0);
  acc1 = wave_sum(acc1);
  acc2 = wave_sum(acc2);
  acc3 = wave_sum(acc3);
  if (lane == 0) {
    float gi_ = acc0 + bih0[0 * HH + j] + bhh0[0 * HH + j];
    float gf_ = acc1 + bih0[1 * HH + j] + bhh0[1 * HH + j];
    float gg_ = acc2 + bih0[2 * HH + j] + bhh0[2 * HH + j];
    float go_ = acc3 + bih0[3 * HH + j] + bhh0[3 * HH + j];
    float c = c0[j];
    float cn = sigf(gf_) * c + sigf(gi_) * tanhf(gg_);
    c0[j] = cn;
    h0_out[j] = sigf(go_) * tanhf(cn);
  }
}

__global__ __launch_bounds__(256) void k_layer1(
    const float* __restrict__ Wih1, const float* __restrict__ Whh1,
    const float* __restrict__ bih1, const float* __restrict__ bhh1,
    float* __restrict__ ws, int t) {
  __shared__ float xs[HH];
  __shared__ float hs[HH];
  float* h0buf = ws;
  float* h1buf = ws + 4096;
  float* c1 = ws + 10240;
  const float* x_in = h0buf + ((t + 1) & 1) * HH;
  const float* h_in = h1buf + (t & 1) * HH;
  float* h_out = h1buf + ((t + 1) & 1) * HH;

  const int tid = threadIdx.x;
  const int b = blockIdx.x;
  for (int k = 0; k < HH / 256; ++k) {
    xs[tid + 256 * k] = x_in[tid + 256 * k];
    hs[tid + 256 * k] = h_in[tid + 256 * k];
  }
  __syncthreads();

  const int wave = tid >> 6, lane = tid & 63;
  const int j = b * 4 + wave;

  float acc0 = 0.f, acc1 = 0.f, acc2 = 0.f, acc3 = 0.f;
  const float4* x4 = (const float4*)xs;
  const float4* h4 = (const float4*)hs;
  const float4* wi0 = (const float4*)(Wih1 + (size_t)(0 * HH + j) * HH);
  const float4* wi1 = (const float4*)(Wih1 + (size_t)(1 * HH + j) * HH);
  const float4* wi2 = (const float4*)(Wih1 + (size_t)(2 * HH + j) * HH);
  const float4* wi3 = (const float4*)(Wih1 + (size_t)(3 * HH + j) * HH);
  const float4* wh0 = (const float4*)(Whh1 + (size_t)(0 * HH + j) * HH);
  const float4* wh1 = (const float4*)(Whh1 + (size_t)(1 * HH + j) * HH);
  const float4* wh2 = (const float4*)(Whh1 + (size_t)(2 * HH + j) * HH);
  const float4* wh3 = (const float4*)(Whh1 + (size_t)(3 * HH + j) * HH);
  for (int s = 0; s < HH / 256; ++s) {
    int e = s * 64 + lane;
    float4 xv = x4[e];
    float4 hv = h4[e];
    float4 a, bb;
    a = wi0[e]; acc0 += a.x * xv.x + a.y * xv.y + a.z * xv.z + a.w * xv.w;
    a = wi1[e]; acc1 += a.x * xv.x + a.y * xv.y + a.z * xv.z + a.w * xv.w;
    a = wi2[e]; acc2 += a.x * xv.x + a.y * xv.y + a.z * xv.z + a.w * xv.w;
    a = wi3[e]; acc3 += a.x * xv.x + a.y * xv.y + a.z * xv.z + a.w * xv.w;
    bb = wh0[e]; acc0 += bb.x * hv.x + bb.y * hv.y + bb.z * hv.z + bb.w * hv.w;
    bb = wh1[e]; acc1 += bb.x * hv.x + bb.y * hv.y + bb.z * hv.z + bb.w * hv.w;
    bb = wh2[e]; acc2 += bb.x * hv.x + bb.y * hv.y + bb.z * hv.z + bb.w * hv.w;
    bb = wh3[e]; acc3 += bb.x * hv.x + bb.y * hv.y + bb.z * hv.z + bb.w * hv.w;
  }
  acc0 = wave_sum(acc0);
  acc1 = wave_sum(acc1);
  acc2 = wave_sum(acc2);
  acc3 = wave_sum(acc3);
  if (lane == 0) {
    float gi_ = acc0 + bih1[0 * HH + j] + bhh1[0 * HH + j];
    float gf_ = acc1 + bih1[1 * HH + j] + bhh1[1 * HH + j];
    float gg_ = acc2 + bih1[2 * HH + j] + bhh1[2 * HH + j];
    float go_ = acc3 + bih1[3 * HH + j] + bhh1[3 * HH + j];
    float c = c1[j];
    float cn = sigf(gf_) * c + sigf(gi_) * tanhf(gg_);
    c1[j] = cn;
    h_out[j] = sigf(go_) * tanhf(cn);
  }
}

__global__ __launch_bounds__(256) void k_logits(
    const float* __restrict__ Wl, const float* __restrict__ bl,
    float* __restrict__ ws, int t) {
  __shared__ float hs[HH];
  __shared__ float lv[16];
  __shared__ float gv[16];
  __shared__ uint32_t kk[2];

  float* h1buf = ws + 4096;
  const float* h1n = h1buf + ((t + 1) & 1) * HH;
  float* logits = ws + 12288;
  float4* partials = (float4*)(ws + 16384);

  const int tid = threadIdx.x;
  const int b = blockIdx.x;
  if (tid == 0) {
    uint32_t k0, k1;
    step_key(t, k0, k1);
    kk[0] = k0; kk[1] = k1;
  }
  for (int k = 0; k < HH / 256; ++k) hs[tid + 256 * k] = h1n[tid + 256 * k];
  __syncthreads();

  const int wave = tid >> 6, lane = tid & 63;
  const float4* h4 = (const float4*)hs;
  for (int q = 0; q < 4; ++q) {
    int jl = wave * 4 + q;
    int j = b * 16 + jl;
    const float4* wr = (const float4*)(Wl + (size_t)j * HH);
    float acc = 0.f;
    for (int s = 0; s < HH / 256; ++s) {
      int e = s * 64 + lane;
      float4 w = wr[e];
      float4 h = h4[e];
      acc += w.x * h.x + w.y * h.y + w.z * h.z + w.w * h.w;
    }
    acc = wave_sum(acc);
    if (lane == 0) {
      float l = acc + bl[j];
      logits[j] = l;
      lv[jl] = l;
      gv[jl] = l + gumbel_for(kk[0], kk[1], j);
    }
  }
  __syncthreads();
  if (tid == 0) {
    float m = -INFINITY, s = 0.f, gm = -INFINITY;
    int gi = 0;
    for (int k = 0; k < 16; ++k) {
      float l = lv[k];
      float m2 = fmaxf(m, l);
      s = s * expf(m - m2) + expf(l - m2);
      m = m2;
      float g = gv[k];
      if (g > gm) { gm = g; gi = b * 16 + k; }
    }
    partials[b] = make_float4(m, s, gm, __int_as_float(gi));
  }
}

__global__ __launch_bounds__(256) void k_final(float* __restrict__ ws,
                                               float* __restrict__ out) {
  __shared__ float4 red[256];
  float* logits = ws + 12288;
  float4* partials = (float4*)(ws + 16384);
  const int tid = threadIdx.x;
  const int b = blockIdx.x;
  red[tid] = partials[tid];
  __syncthreads();
  for (int off = 128; off > 0; off >>= 1) {
    if (tid < off) red[tid] = combine2(red[tid], red[tid + off]);
    __syncthreads();
  }
  float4 r = red[0];
  if (tid < 16) {
    int j = b * 16 + tid;
    out[TT + (size_t)(TT - 1) * OUTW + j] = expf(logits[j] - r.x) / r.y;
  }
  if (b == 0 && tid == 0) out[TT - 1] = (float)__float_as_int(r.w);
}

extern "C" void kernel_launch(void* const* d_in, const int* in_sizes, int n_in,
                              void* d_out, int out_size, void* d_ws, size_t ws_size,
                              hipStream_t stream) {
  (void)in_sizes; (void)n_in; (void)out_size;
  const float* input = (const float*)d_in[0];
  const float* h0i  = (const float*)d_in[1];
  const float* c0i  = (const float*)d_in[2];
  const float* Wih0 = (const float*)d_in[3];
  const float* Whh0 = (const float*)d_in[4];
  const float* bih0 = (const float*)d_in[5];
  const float* bhh0 = (const float*)d_in[6];
  const float* Wih1 = (const float*)d_in[7];
  const float* Whh1 = (const float*)d_in[8];
  const float* bih1 = (const float*)d_in[9];
  const float* bhh1 = (const float*)d_in[10];
  const float* Wl   = (const float*)d_in[11];
  const float* bl   = (const float*)d_in[12];
  float* out = (float*)d_out;
  float* ws = (float*)d_ws;

  if (ws_size >= WS_F16_NEED) {
    _Float16* Whh0h = (_Float16*)((char*)d_ws + W16_BASE);
    _Float16* Wih1h = (_Float16*)((char*)d_ws + W16_BASE + SZ_HH);
    _Float16* Whh1h = (_Float16*)((char*)d_ws + W16_BASE + 2 * SZ_HH);
    _Float16* Wlh   = (_Float16*)((char*)d_ws + W16_BASE + 3 * SZ_HH);
    // 4H*H = 16777216 elems -> 2097152 half8 chunks; Wl = 8388608 -> 1048576
    k_convert<<<8192, 256, 0, stream>>>(Whh0, Whh0h, 2097152);
    k_convert<<<8192, 256, 0, stream>>>(Wih1, Wih1h, 2097152);
    k_convert<<<8192, 256, 0, stream>>>(Whh1, Whh1h, 2097152);
    k_convert<<<4096, 256, 0, stream>>>(Wl, Wlh, 1048576);
    k_init<<<8, 256, 0, stream>>>(h0i, c0i, ws);
    for (int t = 0; t < TT; ++t) {
      k_layer0_f16<<<512, 256, 0, stream>>>(input, Wih0, Whh0h, bih0, bhh0, ws, out, t);
      k_layer1_f16<<<512, 256, 0, stream>>>(Wih1h, Whh1h, bih1, bhh1, ws, t);
      k_logits_f16<<<256, 256, 0, stream>>>(Wlh, bl, ws, t);
    }
    k_final<<<256, 256, 0, stream>>>(ws, out);
  } else {
    k_init<<<8, 256, 0, stream>>>(h0i, c0i, ws);
    for (int t = 0; t < TT; ++t) {
      k_layer0<<<512, 256, 0, stream>>>(input, Wih0, Whh0, bih0, bhh0, ws, out, t);
      k_layer1<<<512, 256, 0, stream>>>(Wih1, Whh1, bih1, bhh1, ws, t);
      k_logits<<<256, 256, 0, stream>>>(Wl, bl, ws, t);
    }
    k_final<<<256, 256, 0, stream>>>(ws, out);
  }
}